// Round 1
// baseline (467.830 us; speedup 1.0000x reference)
//
#include <hip/hip_runtime.h>
#include <stdint.h>

#define N_NODES 50000
#define N_EDGES 800000
#define HID 128
#define NCLS 10
#define NGRAPH 64
#define CAP 64        // bucket capacity; deg ~ Poisson(16), P(max>64) < 1e-20
#define NCHUNK 8
#define CHUNK_F 16
#define CH_STRIDE (N_NODES * CHUNK_F)   // 800000 floats per chunk region
#define AGG_TILES 782                    // ceil(50000/64) 64-node tiles
#define AGG_GRID 1536                    // 8 chunks * 192 blocks; 6 blk/CU co-resident
#define NEW_WS_NEED 83662976

typedef unsigned short ushort_t;
typedef __attribute__((ext_vector_type(8))) short bf16x8;
typedef __attribute__((ext_vector_type(4))) float f32x4;
typedef __attribute__((ext_vector_type(4))) int i32x4;

__device__ __forceinline__ ushort_t f2bf(float f) {
    union { float f; unsigned int i; } v; v.f = f;
    unsigned int u = v.i;
    return (ushort_t)((u + 0x7FFFu + ((u >> 16) & 1u)) >> 16);
}
__device__ __forceinline__ float bf2f(ushort_t u) {
    union { unsigned int i; float f; } v; v.i = ((unsigned int)u) << 16; return v.f;
}
__device__ __forceinline__ void add4(float4& a, const float4& v) {
    a.x += v.x; a.y += v.y; a.z += v.z; a.w += v.w;
}
__device__ __forceinline__ void fmad4(float4& a, float d, const float4& v) {
    a.x = fmaf(d, v.x, a.x); a.y = fmaf(d, v.y, a.y);
    a.z = fmaf(d, v.z, a.z); a.w = fmaf(d, v.w, a.w);
}
// UNSIGNED extraction — (p>>16) on signed int sign-extends for ids>=32768
__device__ __forceinline__ int exhi(int p) { return (p >> 16) & 0xffff; }
__device__ __forceinline__ int exlo(int p) { return p & 0xffff; }

// ---- fused: zero cnt/sums/maxs (blocks 0..195) + bounds/tctr (196) + wsplit (197..388)
__global__ void k_zero(int* cnt, float* sums, float* maxs,
                       const int* __restrict__ batch, int* bound, int* counts,
                       const float* __restrict__ W0, const float* __restrict__ W1,
                       const float* __restrict__ W2, ushort_t* Whi, ushort_t* Wlo,
                       int* tctr) {
    int b = blockIdx.x, t = threadIdx.x;
    if (b < 196) {
        int i = b * 256 + t;
        if (i < N_NODES) cnt[i] = 0;
        if (i < NGRAPH * HID) { sums[i] = 0.f; maxs[i] = 0.f; }
    } else if (b == 196) {
        int g = t;
        if (g <= NGRAPH) {
            int lo = 0, hi = N_NODES;
            while (lo < hi) {
                int mid = (lo + hi) >> 1;
                if (batch[mid] < g) lo = mid + 1; else hi = mid;
            }
            bound[g] = lo;
        }
        if (t >= 128 && t < 152) tctr[t - 128] = 0;   // 3 layers x 8 chunk counters
        __syncthreads();
        if (g < NGRAPH) counts[g] = bound[g + 1] - bound[g];
    } else {
        int gid = (b - 197) * 256 + t;          // 192*256 = 49152 items
        int l = gid / (32 * 512);
        int rem = gid - l * 32 * 512;
        int tile = rem >> 9;
        int p = rem & 511;
        int lane = p >> 3, j = p & 7;
        int kk = tile >> 3, c = tile & 7;
        int k = 32 * kk + (lane >> 4) * 8 + j;
        int n = 16 * c + (lane & 15);
        const float* W = (l == 0) ? W0 : (l == 1) ? W1 : W2;
        float x = W[k * 128 + n];
        ushort_t hi = f2bf(x);
        ushort_t lo = f2bf(x - bf2f(hi));
        Whi[l * 16384 + rem] = hi;
        Wlo[l * 16384 + rem] = lo;
    }
}

// ---- one-pass bucket-CSR fill, 8 edges/thread for atomic MLP ----
__global__ void k_fill(const int* __restrict__ src, const int* __restrict__ dst,
                       int* cnt, ushort_t* csr16) {
    int base = (blockIdx.x * 256 + threadIdx.x) * 8;
    if (base + 7 < N_EDGES) {
        int4 da = *(const int4*)(dst + base);
        int4 db = *(const int4*)(dst + base + 4);
        int4 sa = *(const int4*)(src + base);
        int4 sb = *(const int4*)(src + base + 4);
        int p0 = atomicAdd(&cnt[da.x], 1);
        int p1 = atomicAdd(&cnt[da.y], 1);
        int p2 = atomicAdd(&cnt[da.z], 1);
        int p3 = atomicAdd(&cnt[da.w], 1);
        int p4 = atomicAdd(&cnt[db.x], 1);
        int p5 = atomicAdd(&cnt[db.y], 1);
        int p6 = atomicAdd(&cnt[db.z], 1);
        int p7 = atomicAdd(&cnt[db.w], 1);
        if (p0 < CAP) csr16[da.x * CAP + p0] = (ushort_t)sa.x;
        if (p1 < CAP) csr16[da.y * CAP + p1] = (ushort_t)sa.y;
        if (p2 < CAP) csr16[da.z * CAP + p2] = (ushort_t)sa.z;
        if (p3 < CAP) csr16[da.w * CAP + p3] = (ushort_t)sa.w;
        if (p4 < CAP) csr16[db.x * CAP + p4] = (ushort_t)sb.x;
        if (p5 < CAP) csr16[db.y * CAP + p5] = (ushort_t)sb.y;
        if (p6 < CAP) csr16[db.z * CAP + p6] = (ushort_t)sb.z;
        if (p7 < CAP) csr16[db.w * CAP + p7] = (ushort_t)sb.w;
    } else {
        for (int i = base; i < N_EDGES; i++) {
            int d = dst[i];
            int slot = atomicAdd(&cnt[d], 1);
            if (slot < CAP) csr16[d * CAP + slot] = (ushort_t)src[i];
        }
    }
}

// ---- relayout x row-major -> chunk-major [8][50000][16], prescaled by isd ----
__global__ void k_relayout(const float* __restrict__ x, const int* __restrict__ cnt,
                           float* __restrict__ Xc) {
    int gid = blockIdx.x * 256 + threadIdx.x;     // 8*50000*4 = 1,600,000 exact
    int c = gid / 200000;
    int r2 = gid - c * 200000;
    int i = r2 >> 2, f4 = r2 & 3;
    float isd = rsqrtf((float)cnt[i] + 1.0f);
    f32x4 v = *(const f32x4*)(x + (size_t)i * HID + c * CHUNK_F + f4 * 4);
    f32x4 o;
    o.x = isd * v.x; o.y = isd * v.y; o.z = isd * v.z; o.w = isd * v.w;
    __builtin_nontemporal_store(o, (f32x4*)(Xc + (size_t)c * CH_STRIDE + i * CHUNK_F + f4 * 4));
}

// ---- chunked aggregation: chunk c = blockIdx&7 pins its 3.2MB region to one XCD L2.
// 4 lanes per node (one 64B chunk row), 64 nodes per tile, per-chunk work stealing.
__global__ __launch_bounds__(256, 6)
void k_agg(const float* __restrict__ Hc, const ushort_t* __restrict__ csr16,
           const int* __restrict__ cnt, float* __restrict__ Agg, int* tctr) {
    int c = blockIdx.x & 7;
    int t = threadIdx.x;
    int j = t & 3;                      // lane within 4-lane group
    int bl = (t & 63) & ~3;             // group base lane within wave
    const float* chunk = Hc + (size_t)c * CH_STRIDE;
    float* aggc = Agg + (size_t)c * CH_STRIDE;
    __shared__ int stile;
    for (;;) {
        __syncthreads();
        if (t == 0) stile = atomicAdd(tctr + c, 1);
        __syncthreads();
        int tile = stile;
        if (tile >= AGG_TILES) break;
        int i = tile * 64 + (t >> 2);
        if (i < N_NODES) {
            int ci = cnt[i];
            int m = min(ci, CAP);
            float isd = rsqrtf((float)ci + 1.0f);
            const i32x4* row = (const i32x4*)(csr16 + (size_t)i * CAP);
            i32x4 pk0 = __builtin_nontemporal_load(row + j);      // edges 8j..8j+7
            i32x4 pk1;
            if (m > 32) pk1 = __builtin_nontemporal_load(row + 4 + j);
            // self term: inputs are pre-scaled, factor 1
            f32x4 accA = *(const f32x4*)(chunk + i * CHUNK_F + j * 4);
            f32x4 accB = (f32x4){0.f, 0.f, 0.f, 0.f};
            int full = m >> 3, rem = m & 7;
#pragma unroll
            for (int o = 0; o < 8; ++o) {
                if (o >= full) break;                 // divergent per-group: ok
                i32x4 pks = (o < 4) ? pk0 : pk1;      // static per unrolled copy
                int sl = bl + (o & 3);
                int px = __shfl(pks.x, sl), py = __shfl(pks.y, sl);
                int pz = __shfl(pks.z, sl), pw = __shfl(pks.w, sl);
                int s0 = exlo(px), s1 = exhi(px);
                int s2 = exlo(py), s3 = exhi(py);
                int s4 = exlo(pz), s5 = exhi(pz);
                int s6 = exlo(pw), s7 = exhi(pw);
                f32x4 v0 = *(const f32x4*)(chunk + s0 * CHUNK_F + j * 4);
                f32x4 v1 = *(const f32x4*)(chunk + s1 * CHUNK_F + j * 4);
                f32x4 v2 = *(const f32x4*)(chunk + s2 * CHUNK_F + j * 4);
                f32x4 v3 = *(const f32x4*)(chunk + s3 * CHUNK_F + j * 4);
                f32x4 v4 = *(const f32x4*)(chunk + s4 * CHUNK_F + j * 4);
                f32x4 v5 = *(const f32x4*)(chunk + s5 * CHUNK_F + j * 4);
                f32x4 v6 = *(const f32x4*)(chunk + s6 * CHUNK_F + j * 4);
                f32x4 v7 = *(const f32x4*)(chunk + s7 * CHUNK_F + j * 4);
                accA += (v0 + v1) + (v2 + v3);
                accB += (v4 + v5) + (v6 + v7);
            }
            if (rem) {
                int o = full;
                i32x4 pks = (o < 4) ? pk0 : pk1;
                int sl = bl + (o & 3);
                int px = __shfl(pks.x, sl), py = __shfl(pks.y, sl);
                int pz = __shfl(pks.z, sl), pw = __shfl(pks.w, sl);
#pragma unroll
                for (int k = 0; k < 7; ++k) {
                    if (k < rem) {
                        int comp = k >> 1;
                        int pv = comp == 0 ? px : comp == 1 ? py : comp == 2 ? pz : pw;
                        int s = (k & 1) ? exhi(pv) : exlo(pv);
                        accB += *(const f32x4*)(chunk + s * CHUNK_F + j * 4);
                    }
                }
            }
            f32x4 o4;
            o4.x = isd * (accA.x + accB.x);
            o4.y = isd * (accA.y + accB.y);
            o4.z = isd * (accA.z + accB.z);
            o4.w = isd * (accA.w + accB.w);
            __builtin_nontemporal_store(o4, (f32x4*)(aggc + i * CHUNK_F + j * 4));
        }
    }
}

// ---- dense MFMA tile: reads chunk-major agg rows, writes chunk-major h (or pools) ----
__global__ void k_mm(const float* __restrict__ A, const int* __restrict__ cnt,
                     const ushort_t* __restrict__ Whi, const ushort_t* __restrict__ Wlo,
                     const float* __restrict__ bias, int scale_out, int pool,
                     const int* __restrict__ batch, float* sums, float* maxs,
                     float* __restrict__ Out) {
    __shared__ float T[16][132];
    __shared__ int sg[16];
    int t = threadIdx.x, wv = t >> 6, lane = t & 63;
    if (pool && t < 16) sg[t] = batch[blockIdx.x * 16 + t];
#pragma unroll
    for (int u = 0; u < 2; ++u) {
        int idx = u * 256 + t;                         // 512 f32x4 = 16 rows x 128
        int cch = idx >> 6, nn = (idx >> 2) & 15, f4q = idx & 3;
        int node = blockIdx.x * 16 + nn;               // 3125*16 = 50000 exact
        f32x4 v = __builtin_nontemporal_load(
            (const f32x4*)(A + (size_t)cch * CH_STRIDE + node * CHUNK_F + f4q * 4));
        *(f32x4*)&T[nn][cch * 16 + f4q * 4] = v;
    }
    __syncthreads();

    int mrow = lane & 15, qq = lane >> 4;
    f32x4 acc[2];
    acc[0] = (f32x4){0.f, 0.f, 0.f, 0.f};
    acc[1] = (f32x4){0.f, 0.f, 0.f, 0.f};
#pragma unroll
    for (int kk = 0; kk < 4; kk++) {
        const float* tp = &T[mrow][kk * 32 + qq * 8];
        float4 p0 = *(const float4*)tp;
        float4 p1 = *(const float4*)(tp + 4);
        float av[8] = {p0.x, p0.y, p0.z, p0.w, p1.x, p1.y, p1.z, p1.w};
        bf16x8 ahi, alo;
#pragma unroll
        for (int jj = 0; jj < 8; jj++) {
            ushort_t hbits = f2bf(av[jj]);
            ahi[jj] = (short)hbits;
            alo[jj] = (short)f2bf(av[jj] - bf2f(hbits));
        }
#pragma unroll
        for (int cl = 0; cl < 2; cl++) {
            int c = wv * 2 + cl;
            const bf16x8 bhi = *(const bf16x8*)(Whi + (((kk * 8 + c) * 64 + lane) << 3));
            const bf16x8 blo = *(const bf16x8*)(Wlo + (((kk * 8 + c) * 64 + lane) << 3));
            acc[cl] = __builtin_amdgcn_mfma_f32_16x16x32_bf16(ahi, bhi, acc[cl], 0, 0, 0);
            acc[cl] = __builtin_amdgcn_mfma_f32_16x16x32_bf16(alo, bhi, acc[cl], 0, 0, 0);
            acc[cl] = __builtin_amdgcn_mfma_f32_16x16x32_bf16(ahi, blo, acc[cl], 0, 0, 0);
        }
    }
    int rb = blockIdx.x * 16 + qq * 4;
    if (!pool) {
        float osc[4];
#pragma unroll
        for (int rr = 0; rr < 4; rr++)
            osc[rr] = scale_out ? rsqrtf((float)cnt[rb + rr] + 1.0f) : 1.0f;
#pragma unroll
        for (int cl = 0; cl < 2; cl++) {
            int cc = wv * 2 + cl;                 // chunk index; feat-in-chunk = mrow
            float bcol = bias[cc * 16 + mrow];
#pragma unroll
            for (int rr = 0; rr < 4; rr++) {
                float val = fmaxf(acc[cl][rr] + bcol, 0.f) * osc[rr];
                __builtin_nontemporal_store(val,
                    Out + (size_t)cc * CH_STRIDE + (size_t)(rb + rr) * CHUNK_F + mrow);
            }
        }
    } else {
        __syncthreads();   // all waves done reading T
#pragma unroll
        for (int cl = 0; cl < 2; cl++) {
            int col = (wv * 2 + cl) * 16 + mrow;
            float bcol = bias[col];
#pragma unroll
            for (int rr = 0; rr < 4; rr++)
                T[qq * 4 + rr][col] = fmaxf(acc[cl][rr] + bcol, 0.f);
        }
        __syncthreads();
        int f = t & 127, half = t >> 7;   // half 0: sums, half 1: maxs
        int cur = sg[0];
        float s = 0.f, mx = 0.f;
        for (int r = 0; r < 16; r++) {
            int g = sg[r];
            if (g != cur) {
                if (half == 0) atomicAdd(&sums[cur * HID + f], s);
                else atomicMax((int*)&maxs[cur * HID + f], __float_as_int(mx));
                s = 0.f; mx = 0.f; cur = g;
            }
            float v = T[r][f];
            s += v;
            mx = fmaxf(mx, v);
        }
        if (half == 0) atomicAdd(&sums[cur * HID + f], s);
        else atomicMax((int*)&maxs[cur * HID + f], __float_as_int(mx));
    }
}

// ---------------- fallback fused layer (row-major gather) — verified path -----------
__global__ void k_layer(const float* __restrict__ In, const ushort_t* __restrict__ csr16,
                        const int* __restrict__ cnt,
                        const ushort_t* __restrict__ Whi, const ushort_t* __restrict__ Wlo,
                        const float* __restrict__ bias, int pre_scaled, int scale_out,
                        int pool, const int* __restrict__ batch,
                        float* sums, float* maxs, float* __restrict__ Out) {
    __shared__ float T[16][132];
    __shared__ int sg[16];
    int t = threadIdx.x, wv = t >> 6, lane = t & 63;
    int hl = lane & 31, q = lane >> 5;
    if (pool && t < 16) sg[t] = batch[blockIdx.x * 16 + t];

    for (int r = 0; r < 4; r++) {
        int i = blockIdx.x * 16 + wv * 4 + r;
        int ci = cnt[i];
        int m = min(ci, CAP);
        float isdi = rsqrtf((float)ci + 1.0f);
        int packed = ((const int*)(csr16 + (size_t)i * CAP))[hl];
        float4 self = *(const float4*)(In + (size_t)i * 128 + hl * 4);
        float sfac = pre_scaled ? 1.0f : isdi;
        float4 a0 = make_float4(0.f, 0.f, 0.f, 0.f);
        float4 a1 = a0, a2 = a0, a3 = a0;
        if (q == 0) { a0.x = sfac * self.x; a0.y = sfac * self.y;
                      a0.z = sfac * self.z; a0.w = sfac * self.w; }
        int e = 0;
        if (pre_scaled) {
            for (; e + 7 < m; e += 8) {
                int k0 = e >> 1;
                int p0 = __shfl(packed, k0);
                int p1 = __shfl(packed, k0 + 1);
                int p2 = __shfl(packed, k0 + 2);
                int p3 = __shfl(packed, k0 + 3);
                int s0 = q ? exhi(p0) : exlo(p0);
                int s1 = q ? exhi(p1) : exlo(p1);
                int s2 = q ? exhi(p2) : exlo(p2);
                int s3 = q ? exhi(p3) : exlo(p3);
                float4 v0 = *(const float4*)(In + (size_t)s0 * 128 + hl * 4);
                float4 v1 = *(const float4*)(In + (size_t)s1 * 128 + hl * 4);
                float4 v2 = *(const float4*)(In + (size_t)s2 * 128 + hl * 4);
                float4 v3 = *(const float4*)(In + (size_t)s3 * 128 + hl * 4);
                add4(a0, v0); add4(a1, v1); add4(a2, v2); add4(a3, v3);
            }
            for (; e + 1 < m; e += 2) {
                int p = __shfl(packed, e >> 1);
                int s0 = q ? exhi(p) : exlo(p);
                float4 v0 = *(const float4*)(In + (size_t)s0 * 128 + hl * 4);
                add4(a0, v0);
            }
            if (e < m && q == 0) {
                int p = __shfl(packed, e >> 1);
                int s0 = exlo(p);
                float4 v0 = *(const float4*)(In + (size_t)s0 * 128 + hl * 4);
                add4(a0, v0);
            }
        } else {
            for (; e + 7 < m; e += 8) {
                int k0 = e >> 1;
                int p0 = __shfl(packed, k0);
                int p1 = __shfl(packed, k0 + 1);
                int p2 = __shfl(packed, k0 + 2);
                int p3 = __shfl(packed, k0 + 3);
                int s0 = q ? exhi(p0) : exlo(p0);
                int s1 = q ? exhi(p1) : exlo(p1);
                int s2 = q ? exhi(p2) : exlo(p2);
                int s3 = q ? exhi(p3) : exlo(p3);
                float d0 = rsqrtf((float)cnt[s0] + 1.0f);
                float d1 = rsqrtf((float)cnt[s1] + 1.0f);
                float d2 = rsqrtf((float)cnt[s2] + 1.0f);
                float d3 = rsqrtf((float)cnt[s3] + 1.0f);
                float4 v0 = *(const float4*)(In + (size_t)s0 * 128 + hl * 4);
                float4 v1 = *(const float4*)(In + (size_t)s1 * 128 + hl * 4);
                float4 v2 = *(const float4*)(In + (size_t)s2 * 128 + hl * 4);
                float4 v3 = *(const float4*)(In + (size_t)s3 * 128 + hl * 4);
                fmad4(a0, d0, v0); fmad4(a1, d1, v1);
                fmad4(a2, d2, v2); fmad4(a3, d3, v3);
            }
            for (; e + 1 < m; e += 2) {
                int p = __shfl(packed, e >> 1);
                int s0 = q ? exhi(p) : exlo(p);
                float d0 = rsqrtf((float)cnt[s0] + 1.0f);
                float4 v0 = *(const float4*)(In + (size_t)s0 * 128 + hl * 4);
                fmad4(a0, d0, v0);
            }
            if (e < m && q == 0) {
                int p = __shfl(packed, e >> 1);
                int s0 = exlo(p);
                float d0 = rsqrtf((float)cnt[s0] + 1.0f);
                float4 v0 = *(const float4*)(In + (size_t)s0 * 128 + hl * 4);
                fmad4(a0, d0, v0);
            }
        }
        float4 s4;
        s4.x = (a0.x + a1.x) + (a2.x + a3.x);
        s4.y = (a0.y + a1.y) + (a2.y + a3.y);
        s4.z = (a0.z + a1.z) + (a2.z + a3.z);
        s4.w = (a0.w + a1.w) + (a2.w + a3.w);
        s4.x += __shfl_xor(s4.x, 32);
        s4.y += __shfl_xor(s4.y, 32);
        s4.z += __shfl_xor(s4.z, 32);
        s4.w += __shfl_xor(s4.w, 32);
        if (q == 0) {
            float4 o;
            o.x = isdi * s4.x; o.y = isdi * s4.y;
            o.z = isdi * s4.z; o.w = isdi * s4.w;
            *(float4*)&T[wv * 4 + r][hl * 4] = o;
        }
    }
    __syncthreads();

    int mrow = lane & 15, qq = lane >> 4;
    f32x4 acc[2];
    acc[0] = (f32x4){0.f, 0.f, 0.f, 0.f};
    acc[1] = (f32x4){0.f, 0.f, 0.f, 0.f};
#pragma unroll
    for (int kk = 0; kk < 4; kk++) {
        const float* tp = &T[mrow][kk * 32 + qq * 8];
        float4 p0 = *(const float4*)tp;
        float4 p1 = *(const float4*)(tp + 4);
        float av[8] = {p0.x, p0.y, p0.z, p0.w, p1.x, p1.y, p1.z, p1.w};
        bf16x8 ahi, alo;
#pragma unroll
        for (int j = 0; j < 8; j++) {
            ushort_t hbits = f2bf(av[j]);
            ahi[j] = (short)hbits;
            alo[j] = (short)f2bf(av[j] - bf2f(hbits));
        }
#pragma unroll
        for (int cl = 0; cl < 2; cl++) {
            int c = wv * 2 + cl;
            const bf16x8 bhi = *(const bf16x8*)(Whi + (((kk * 8 + c) * 64 + lane) << 3));
            const bf16x8 blo = *(const bf16x8*)(Wlo + (((kk * 8 + c) * 64 + lane) << 3));
            acc[cl] = __builtin_amdgcn_mfma_f32_16x16x32_bf16(ahi, bhi, acc[cl], 0, 0, 0);
            acc[cl] = __builtin_amdgcn_mfma_f32_16x16x32_bf16(alo, bhi, acc[cl], 0, 0, 0);
            acc[cl] = __builtin_amdgcn_mfma_f32_16x16x32_bf16(ahi, blo, acc[cl], 0, 0, 0);
        }
    }
    int rb = blockIdx.x * 16 + qq * 4;
    if (!pool) {
        float osc[4];
#pragma unroll
        for (int rr = 0; rr < 4; rr++)
            osc[rr] = scale_out ? rsqrtf((float)cnt[rb + rr] + 1.0f) : 1.0f;
#pragma unroll
        for (int cl = 0; cl < 2; cl++) {
            int col = (wv * 2 + cl) * 16 + mrow;
            float bcol = bias[col];
#pragma unroll
            for (int rr = 0; rr < 4; rr++) {
                float val = fmaxf(acc[cl][rr] + bcol, 0.f);
                Out[(size_t)(rb + rr) * 128 + col] = val * osc[rr];
            }
        }
    } else {
        __syncthreads();
#pragma unroll
        for (int cl = 0; cl < 2; cl++) {
            int col = (wv * 2 + cl) * 16 + mrow;
            float bcol = bias[col];
#pragma unroll
            for (int rr = 0; rr < 4; rr++)
                T[qq * 4 + rr][col] = fmaxf(acc[cl][rr] + bcol, 0.f);
        }
        __syncthreads();
        int f = t & 127, half = t >> 7;
        int cur = sg[0];
        float s = 0.f, mx = 0.f;
        for (int r = 0; r < 16; r++) {
            int g = sg[r];
            if (g != cur) {
                if (half == 0) atomicAdd(&sums[cur * HID + f], s);
                else atomicMax((int*)&maxs[cur * HID + f], __float_as_int(mx));
                s = 0.f; mx = 0.f; cur = g;
            }
            float v = T[r][f];
            s += v;
            mx = fmaxf(mx, v);
        }
        if (half == 0) atomicAdd(&sums[cur * HID + f], s);
        else atomicMax((int*)&maxs[cur * HID + f], __float_as_int(mx));
    }
}

// ---------------- head ----------------
__global__ void k_final(const float* __restrict__ sums, const float* __restrict__ maxs,
                        const int* __restrict__ counts, const float* __restrict__ Wa,
                        const float* __restrict__ ba, float* __restrict__ out) {
    __shared__ float a[256];
    __shared__ float red[4];
    int g = blockIdx.x, t = threadIdx.x;
    float denom = fmaxf((float)counts[g], 1.f);
    float val = (t < 128) ? (sums[g * HID + t] / denom) : maxs[g * HID + (t - 128)];
    a[t] = val;
    out[NGRAPH * NCLS + g * 256 + t] = val;
    __syncthreads();
    for (int c = 0; c < NCLS; c++) {
        float p = a[t] * Wa[t * NCLS + c];
        for (int o = 32; o > 0; o >>= 1) p += __shfl_down(p, o);
        if ((t & 63) == 0) red[t >> 6] = p;
        __syncthreads();
        if (t == 0) {
            out[g * NCLS + c] = red[0] + red[1] + red[2] + red[3] + ba[c];
        }
        __syncthreads();
    }
}

extern "C" void kernel_launch(void* const* d_in, const int* in_sizes, int n_in,
                              void* d_out, int out_size, void* d_ws, size_t ws_size,
                              hipStream_t stream) {
    const float* x = (const float*)d_in[0];
    const int* ei = (const int*)d_in[1];
    const int* src = ei;
    const int* dst = ei + N_EDGES;
    const int* batch = (const int*)d_in[2];
    const float* W0 = (const float*)d_in[3];
    const float* b0 = (const float*)d_in[4];
    const float* W1 = (const float*)d_in[5];
    const float* b1 = (const float*)d_in[6];
    const float* W2 = (const float*)d_in[7];
    const float* b2 = (const float*)d_in[8];
    const float* Wa = (const float*)d_in[9];
    const float* ba = (const float*)d_in[10];
    float* out = (float*)d_out;

    char* ws = (char*)d_ws;
    int*      cnt    = (int*)(ws + 0);             // 50000 i32
    int*      bound  = (int*)(ws + 200192);        // 65 i32
    int*      tctr   = (int*)(ws + 200464);        // 24 i32 (work-steal counters)
    int*      counts = (int*)(ws + 200576);        // 64 i32
    float*    sums   = (float*)(ws + 200832);      // 8192 f32
    float*    maxs   = (float*)(ws + 233600);      // 8192 f32
    ushort_t* Whi    = (ushort_t*)(ws + 266368);   // 3*16384 bf16
    ushort_t* Wlo    = (ushort_t*)(ws + 364672);   // 3*16384 bf16
    ushort_t* csr16  = (ushort_t*)(ws + 462976);   // 50000*64 u16 (6.4 MB)
    float*    bufX   = (float*)(ws + 6862976);     // 25.6 MB (Xc / h1)
    float*    bufA   = (float*)(ws + 32462976);    // 25.6 MB (agg)
    float*    bufB   = (float*)(ws + 58062976);    // 25.6 MB (h0) — new path only
    // new-path total: 83,662,976 B

    k_zero<<<389, 256, 0, stream>>>(cnt, sums, maxs, batch, bound, counts,
                                    W0, W1, W2, Whi, Wlo, tctr);
    k_fill<<<391, 256, 0, stream>>>(src, dst, cnt, csr16);

    if (ws_size >= (size_t)NEW_WS_NEED) {
        // chunked, XCD-resident aggregation + dense MFMA per layer
        k_relayout<<<6250, 256, 0, stream>>>(x, cnt, bufX);
        k_agg<<<AGG_GRID, 256, 0, stream>>>(bufX, csr16, cnt, bufA, tctr);
        k_mm<<<3125, 256, 0, stream>>>(bufA, cnt, Whi, Wlo, b0, 1, 0,
                                       batch, sums, maxs, bufB);
        k_agg<<<AGG_GRID, 256, 0, stream>>>(bufB, csr16, cnt, bufA, tctr + 8);
        k_mm<<<3125, 256, 0, stream>>>(bufA, cnt, Whi + 16384, Wlo + 16384, b1, 1, 0,
                                       batch, sums, maxs, bufX);
        k_agg<<<AGG_GRID, 256, 0, stream>>>(bufX, csr16, cnt, bufA, tctr + 16);
        k_mm<<<3125, 256, 0, stream>>>(bufA, cnt, Whi + 32768, Wlo + 32768, b2, 0, 1,
                                       batch, sums, maxs, bufB);
    } else {
        // fallback: verified fused path (fits 58.1 MB)
        k_layer<<<3125, 256, 0, stream>>>(x, csr16, cnt, Whi, Wlo, b0, 0, 1,
                                          0, batch, sums, maxs, bufX);
        k_layer<<<3125, 256, 0, stream>>>(bufX, csr16, cnt, Whi + 16384, Wlo + 16384, b1, 1, 1,
                                          0, batch, sums, maxs, bufA);
        k_layer<<<3125, 256, 0, stream>>>(bufA, csr16, cnt, Whi + 32768, Wlo + 32768, b2, 1, 0,
                                          1, batch, sums, maxs, bufX);
    }

    k_final<<<NGRAPH, 256, 0, stream>>>(sums, maxs, counts, Wa, ba, out);
}

// Round 4
// 283.892 us; speedup vs baseline: 1.6479x; 1.6479x over previous
//
#include <hip/hip_runtime.h>
#include <stdint.h>

#define N_NODES 50000
#define N_EDGES 800000
#define HID 128
#define NCLS 10
#define NGRAPH 64
#define CAP 64   // bucket capacity; deg ~ Poisson(16), P(max>64) < 1e-20

typedef unsigned short ushort_t;
typedef __attribute__((ext_vector_type(8))) short bf16x8;
typedef __attribute__((ext_vector_type(8))) short s16x8;
typedef __attribute__((ext_vector_type(4))) short s16x4;
typedef __attribute__((ext_vector_type(4))) float f32x4;

__device__ __forceinline__ ushort_t f2bf(float f) {
    union { float f; unsigned int i; } v; v.f = f;
    unsigned int u = v.i;
    return (ushort_t)((u + 0x7FFFu + ((u >> 16) & 1u)) >> 16);
}
__device__ __forceinline__ float bf2f(ushort_t u) {
    union { unsigned int i; float f; } v; v.i = ((unsigned int)u) << 16; return v.f;
}
// UNSIGNED extraction — (p>>16) on signed int sign-extends for ids>=32768
__device__ __forceinline__ int exhi(int p) { return (p >> 16) & 0xffff; }
__device__ __forceinline__ int exlo(int p) { return p & 0xffff; }
// dequant-fma: a += c * (float)v[k], k=0..3
__device__ __forceinline__ void fmad4q(float4& a, float c, s16x4 v) {
    a.x = fmaf(c, (float)v[0], a.x);
    a.y = fmaf(c, (float)v[1], a.y);
    a.z = fmaf(c, (float)v[2], a.z);
    a.w = fmaf(c, (float)v[3], a.w);
}

// ---- fused: zero cnt/sums/maxs (blocks 0..195) + bounds (196) + wsplit (197..388)
__global__ void k_zero(int* cnt, float* sums, float* maxs,
                       const int* __restrict__ batch, int* bound, int* counts,
                       const float* __restrict__ W0, const float* __restrict__ W1,
                       const float* __restrict__ W2, ushort_t* Whi, ushort_t* Wlo) {
    int b = blockIdx.x, t = threadIdx.x;
    if (b < 196) {
        int i = b * 256 + t;
        if (i < N_NODES) cnt[i] = 0;
        if (i < NGRAPH * HID) { sums[i] = 0.f; maxs[i] = 0.f; }
    } else if (b == 196) {
        int g = t;
        if (g <= NGRAPH) {
            int lo = 0, hi = N_NODES;
            while (lo < hi) {
                int mid = (lo + hi) >> 1;
                if (batch[mid] < g) lo = mid + 1; else hi = mid;
            }
            bound[g] = lo;
        }
        __syncthreads();
        if (g < NGRAPH) counts[g] = bound[g + 1] - bound[g];
    } else {
        int gid = (b - 197) * 256 + t;          // 192*256 = 49152 items
        int l = gid / (32 * 512);
        int rem = gid - l * 32 * 512;
        int tile = rem >> 9;
        int p = rem & 511;
        int lane = p >> 3, j = p & 7;
        int kk = tile >> 3, c = tile & 7;
        int k = 32 * kk + (lane >> 4) * 8 + j;
        int n = 16 * c + (lane & 15);
        const float* W = (l == 0) ? W0 : (l == 1) ? W1 : W2;
        float x = W[k * 128 + n];
        ushort_t hi = f2bf(x);
        ushort_t lo = f2bf(x - bf2f(hi));
        Whi[l * 16384 + rem] = hi;
        Wlo[l * 16384 + rem] = lo;
    }
}

// ---- one-pass bucket-CSR fill, 8 edges/thread for atomic MLP ----
__global__ void k_fill(const int* __restrict__ src, const int* __restrict__ dst,
                       int* cnt, ushort_t* csr16) {
    int base = (blockIdx.x * 256 + threadIdx.x) * 8;
    if (base + 7 < N_EDGES) {
        int4 da = *(const int4*)(dst + base);
        int4 db = *(const int4*)(dst + base + 4);
        int4 sa = *(const int4*)(src + base);
        int4 sb = *(const int4*)(src + base + 4);
        int p0 = atomicAdd(&cnt[da.x], 1);
        int p1 = atomicAdd(&cnt[da.y], 1);
        int p2 = atomicAdd(&cnt[da.z], 1);
        int p3 = atomicAdd(&cnt[da.w], 1);
        int p4 = atomicAdd(&cnt[db.x], 1);
        int p5 = atomicAdd(&cnt[db.y], 1);
        int p6 = atomicAdd(&cnt[db.z], 1);
        int p7 = atomicAdd(&cnt[db.w], 1);
        if (p0 < CAP) csr16[da.x * CAP + p0] = (ushort_t)sa.x;
        if (p1 < CAP) csr16[da.y * CAP + p1] = (ushort_t)sa.y;
        if (p2 < CAP) csr16[da.z * CAP + p2] = (ushort_t)sa.z;
        if (p3 < CAP) csr16[da.w * CAP + p3] = (ushort_t)sa.w;
        if (p4 < CAP) csr16[db.x * CAP + p4] = (ushort_t)sb.x;
        if (p5 < CAP) csr16[db.y * CAP + p5] = (ushort_t)sb.y;
        if (p6 < CAP) csr16[db.z * CAP + p6] = (ushort_t)sb.z;
        if (p7 < CAP) csr16[db.w * CAP + p7] = (ushort_t)sb.w;
    } else {
        for (int i = base; i < N_EDGES; i++) {
            int d = dst[i];
            int slot = atomicAdd(&cnt[d], 1);
            if (slot < CAP) csr16[d * CAP + slot] = (ushort_t)src[i];
        }
    }
}

// ---- convert x -> int16 rows, pre-scaled by 1/sqrt(deg+1), exact per-row scale ----
// one wave per row: lane l handles elems 2l, 2l+1
__global__ void k_cvt(const float* __restrict__ x, const int* __restrict__ cnt,
                      short* __restrict__ X16, float* __restrict__ Rs) {
    int w = (blockIdx.x * 256 + threadIdx.x) >> 6;   // 12500*4 = 50000 rows
    int l = threadIdx.x & 63;
    float isd = rsqrtf((float)cnt[w] + 1.0f);
    float2 v = *(const float2*)(x + (size_t)w * HID + l * 2);
    float a = isd * v.x, b = isd * v.y;
    float m = fmaxf(fabsf(a), fabsf(b));
#pragma unroll
    for (int o = 1; o < 64; o <<= 1) m = fmaxf(m, __shfl_xor(m, o));
    float sdec = fmaxf(m, 1e-20f) * (1.0f / 32767.0f);
    float inv = 1.0f / sdec;
    int q0 = (int)rintf(a * inv);
    int q1 = (int)rintf(b * inv);
    ((int*)(X16 + (size_t)w * HID))[l] = (q0 & 0xffff) | (q1 << 16);
    if (l == 0) Rs[w] = sdec;
}

// ---------------- fused layer: round-0-verified gather control flow ---------------
// Table = int16 of isd_j * h_j with per-row fp32 scale Rs. Wave wv: nodes blk*16+wv*4+r.
// Lane split (round 0): hl = lane&31 -> 4-feature group (8B); q = lane>>5 -> edge parity.
__global__ void k_layer(const short* __restrict__ In, const float* __restrict__ Rs,
                        const ushort_t* __restrict__ csr16, const int* __restrict__ cnt,
                        const ushort_t* __restrict__ Whi, const ushort_t* __restrict__ Wlo,
                        const float* __restrict__ bias, int scale_out,
                        int pool, const int* __restrict__ batch,
                        float* sums, float* maxs,
                        short* __restrict__ Out, float* __restrict__ RsOut) {
    __shared__ float T[16][132];
    __shared__ int sg[16];
    int t = threadIdx.x, wv = t >> 6, lane = t & 63;
    int hl = lane & 31, q = lane >> 5;   // half-lane, half-index (round-0 layout)
    if (pool && t < 16) sg[t] = batch[blockIdx.x * 16 + t];

    // ---- gather phase: wave wv aggregates nodes (block*16 + wv*4 + r)
    for (int r = 0; r < 4; r++) {
        int i = blockIdx.x * 16 + wv * 4 + r;      // 3125*16 = 50000 exact
        int ci = cnt[i];
        int m = min(ci, CAP);
        float isdi = rsqrtf((float)ci + 1.0f);
        // preload full index row: int k holds edges 2k (lo16), 2k+1 (hi16)
        int packed = ((const int*)(csr16 + (size_t)i * CAP))[hl];
        float4 a0 = make_float4(0.f, 0.f, 0.f, 0.f);
        float4 a1 = a0, a2 = a0, a3 = a0;
        if (q == 0) {
            float cs = Rs[i];
            s16x4 sv = *(const s16x4*)(In + (size_t)i * HID + hl * 4);
            fmad4q(a0, cs, sv);                    // self term (pre-scaled table)
        }
        int e = 0;
        for (; e + 7 < m; e += 8) {
            int k0 = e >> 1;
            int p0 = __shfl(packed, k0);
            int p1 = __shfl(packed, k0 + 1);
            int p2 = __shfl(packed, k0 + 2);
            int p3 = __shfl(packed, k0 + 3);
            int s0 = q ? exhi(p0) : exlo(p0);
            int s1 = q ? exhi(p1) : exlo(p1);
            int s2 = q ? exhi(p2) : exlo(p2);
            int s3 = q ? exhi(p3) : exlo(p3);
            float c0 = Rs[s0];
            float c1 = Rs[s1];
            float c2 = Rs[s2];
            float c3 = Rs[s3];
            s16x4 v0 = *(const s16x4*)(In + (size_t)s0 * HID + hl * 4);
            s16x4 v1 = *(const s16x4*)(In + (size_t)s1 * HID + hl * 4);
            s16x4 v2 = *(const s16x4*)(In + (size_t)s2 * HID + hl * 4);
            s16x4 v3 = *(const s16x4*)(In + (size_t)s3 * HID + hl * 4);
            fmad4q(a0, c0, v0); fmad4q(a1, c1, v1);
            fmad4q(a2, c2, v2); fmad4q(a3, c3, v3);
        }
        for (; e + 1 < m; e += 2) {
            int p = __shfl(packed, e >> 1);
            int s0 = q ? exhi(p) : exlo(p);
            float c0 = Rs[s0];
            s16x4 v0 = *(const s16x4*)(In + (size_t)s0 * HID + hl * 4);
            fmad4q(a0, c0, v0);
        }
        if (e < m && q == 0) {
            int p = __shfl(packed, e >> 1);
            int s0 = exlo(p);
            float c0 = Rs[s0];
            s16x4 v0 = *(const s16x4*)(In + (size_t)s0 * HID + hl * 4);
            fmad4q(a0, c0, v0);
        }
        float4 s4;
        s4.x = (a0.x + a1.x) + (a2.x + a3.x);
        s4.y = (a0.y + a1.y) + (a2.y + a3.y);
        s4.z = (a0.z + a1.z) + (a2.z + a3.z);
        s4.w = (a0.w + a1.w) + (a2.w + a3.w);
        // combine the two halves (lane ^ 32 partner holds the other parity's sum)
        s4.x += __shfl_xor(s4.x, 32);
        s4.y += __shfl_xor(s4.y, 32);
        s4.z += __shfl_xor(s4.z, 32);
        s4.w += __shfl_xor(s4.w, 32);
        if (q == 0) {
            float4 o;
            o.x = isdi * s4.x; o.y = isdi * s4.y;
            o.z = isdi * s4.z; o.w = isdi * s4.w;
            *(float4*)&T[wv * 4 + r][hl * 4] = o;
        }
    }
    __syncthreads();

    // ---- MFMA phase: wave wv -> cols [wv*32, wv*32+32)
    int mrow = lane & 15, qq = lane >> 4;
    f32x4 acc[2];
    acc[0] = (f32x4){0.f, 0.f, 0.f, 0.f};
    acc[1] = (f32x4){0.f, 0.f, 0.f, 0.f};
#pragma unroll
    for (int kk = 0; kk < 4; kk++) {
        const float* tp = &T[mrow][kk * 32 + qq * 8];
        float4 p0 = *(const float4*)tp;
        float4 p1 = *(const float4*)(tp + 4);
        float av[8] = {p0.x, p0.y, p0.z, p0.w, p1.x, p1.y, p1.z, p1.w};
        bf16x8 ahi, alo;
#pragma unroll
        for (int j = 0; j < 8; j++) {
            ushort_t hbits = f2bf(av[j]);
            ahi[j] = (short)hbits;
            alo[j] = (short)f2bf(av[j] - bf2f(hbits));
        }
#pragma unroll
        for (int cl = 0; cl < 2; cl++) {
            int c = wv * 2 + cl;
            const bf16x8 bhi = *(const bf16x8*)(Whi + (((kk * 8 + c) * 64 + lane) << 3));
            const bf16x8 blo = *(const bf16x8*)(Wlo + (((kk * 8 + c) * 64 + lane) << 3));
            acc[cl] = __builtin_amdgcn_mfma_f32_16x16x32_bf16(ahi, bhi, acc[cl], 0, 0, 0);
            acc[cl] = __builtin_amdgcn_mfma_f32_16x16x32_bf16(alo, bhi, acc[cl], 0, 0, 0);
            acc[cl] = __builtin_amdgcn_mfma_f32_16x16x32_bf16(ahi, blo, acc[cl], 0, 0, 0);
        }
    }
    // epilogue: C/D col = mrow, row = qq*4+rr
    int rb = blockIdx.x * 16 + qq * 4;
    if (!pool) {
        float osc[4];
#pragma unroll
        for (int rr = 0; rr < 4; rr++)
            osc[rr] = scale_out ? rsqrtf((float)cnt[rb + rr] + 1.0f) : 1.0f;
        __syncthreads();   // all waves done reading T for A-fragments
#pragma unroll
        for (int cl = 0; cl < 2; cl++) {
            int col = (wv * 2 + cl) * 16 + mrow;
            float bcol = bias[col];
#pragma unroll
            for (int rr = 0; rr < 4; rr++)
                T[qq * 4 + rr][col] = fmaxf(acc[cl][rr] + bcol, 0.f) * osc[rr];
        }
        __syncthreads();
        // per-row exact scale + int16 quantize: 16 rows x 16 lanes
        int rr2 = t >> 4, ll = t & 15;
        const float* tp = &T[rr2][ll * 8];
        float4 v0 = *(const float4*)tp;
        float4 v1 = *(const float4*)(tp + 4);
        float mxv = fmaxf(fmaxf(fmaxf(v0.x, v0.y), fmaxf(v0.z, v0.w)),
                          fmaxf(fmaxf(v1.x, v1.y), fmaxf(v1.z, v1.w)));
#pragma unroll
        for (int o = 1; o < 16; o <<= 1) mxv = fmaxf(mxv, __shfl_xor(mxv, o));
        float sdec = fmaxf(mxv, 1e-20f) * (1.0f / 32767.0f);
        float inv = 1.0f / sdec;
        s16x8 qv;
        qv[0] = (short)(int)rintf(v0.x * inv);
        qv[1] = (short)(int)rintf(v0.y * inv);
        qv[2] = (short)(int)rintf(v0.z * inv);
        qv[3] = (short)(int)rintf(v0.w * inv);
        qv[4] = (short)(int)rintf(v1.x * inv);
        qv[5] = (short)(int)rintf(v1.y * inv);
        qv[6] = (short)(int)rintf(v1.z * inv);
        qv[7] = (short)(int)rintf(v1.w * inv);
        int orow = blockIdx.x * 16 + rr2;
        *(s16x8*)(Out + (size_t)orow * HID + ll * 8) = qv;
        if (ll == 0) RsOut[orow] = sdec;
    } else {
        // write relu'd values back into T (rows x feats), then block pool-reduce
        __syncthreads();   // all waves done reading T
#pragma unroll
        for (int cl = 0; cl < 2; cl++) {
            int col = (wv * 2 + cl) * 16 + mrow;
            float bcol = bias[col];
#pragma unroll
            for (int rr = 0; rr < 4; rr++)
                T[qq * 4 + rr][col] = fmaxf(acc[cl][rr] + bcol, 0.f);
        }
        __syncthreads();
        int f = t & 127, half = t >> 7;   // half 0: sums, half 1: maxs
        int cur = sg[0];
        float s = 0.f, mx = 0.f;
        for (int r = 0; r < 16; r++) {
            int g = sg[r];
            if (g != cur) {
                if (half == 0) atomicAdd(&sums[cur * HID + f], s);
                else atomicMax((int*)&maxs[cur * HID + f], __float_as_int(mx));
                s = 0.f; mx = 0.f; cur = g;
            }
            float v = T[r][f];
            s += v;
            mx = fmaxf(mx, v);
        }
        if (half == 0) atomicAdd(&sums[cur * HID + f], s);
        else atomicMax((int*)&maxs[cur * HID + f], __float_as_int(mx));
    }
}

// ---------------- head ----------------
__global__ void k_final(const float* __restrict__ sums, const float* __restrict__ maxs,
                        const int* __restrict__ counts, const float* __restrict__ Wa,
                        const float* __restrict__ ba, float* __restrict__ out) {
    __shared__ float a[256];
    __shared__ float red[4];
    int g = blockIdx.x, t = threadIdx.x;
    float denom = fmaxf((float)counts[g], 1.f);
    float val = (t < 128) ? (sums[g * HID + t] / denom) : maxs[g * HID + (t - 128)];
    a[t] = val;
    out[NGRAPH * NCLS + g * 256 + t] = val;
    __syncthreads();
    for (int c = 0; c < NCLS; c++) {
        float p = a[t] * Wa[t * NCLS + c];
        for (int o = 32; o > 0; o >>= 1) p += __shfl_down(p, o);
        if ((t & 63) == 0) red[t >> 6] = p;
        __syncthreads();
        if (t == 0) {
            out[g * NCLS + c] = red[0] + red[1] + red[2] + red[3] + ba[c];
        }
        __syncthreads();
    }
}

extern "C" void kernel_launch(void* const* d_in, const int* in_sizes, int n_in,
                              void* d_out, int out_size, void* d_ws, size_t ws_size,
                              hipStream_t stream) {
    const float* x = (const float*)d_in[0];
    const int* ei = (const int*)d_in[1];
    const int* src = ei;
    const int* dst = ei + N_EDGES;
    const int* batch = (const int*)d_in[2];
    const float* W0 = (const float*)d_in[3];
    const float* b0 = (const float*)d_in[4];
    const float* W1 = (const float*)d_in[5];
    const float* b1 = (const float*)d_in[6];
    const float* W2 = (const float*)d_in[7];
    const float* b2 = (const float*)d_in[8];
    const float* Wa = (const float*)d_in[9];
    const float* ba = (const float*)d_in[10];
    float* out = (float*)d_out;

    char* ws = (char*)d_ws;
    int*      cnt    = (int*)(ws + 0);             // 50000 i32
    int*      bound  = (int*)(ws + 200192);        // 65 i32
    int*      counts = (int*)(ws + 200576);        // 64 i32
    float*    sums   = (float*)(ws + 200832);      // 8192 f32
    float*    maxs   = (float*)(ws + 233600);      // 8192 f32
    ushort_t* Whi    = (ushort_t*)(ws + 266368);   // 3*16384 bf16
    ushort_t* Wlo    = (ushort_t*)(ws + 364672);   // 3*16384 bf16
    ushort_t* csr16  = (ushort_t*)(ws + 462976);   // 50000*64 u16 (6.4 MB)
    float*    RsX    = (float*)(ws + 6862976);     // 50000 f32 row scales
    float*    RsA    = (float*)(ws + 7062976);
    float*    RsB    = (float*)(ws + 7262976);
    short*    X16    = (short*)(ws + 7462976);     // 50000x128 i16 (12.8 MB)
    short*    hA     = (short*)(ws + 20262976);    // 50000x128 i16
    short*    hB     = (short*)(ws + 33062976);    // 50000x128 i16
    // total 45,862,976 B

    k_zero<<<389, 256, 0, stream>>>(cnt, sums, maxs, batch, bound, counts,
                                    W0, W1, W2, Whi, Wlo);
    k_fill<<<391, 256, 0, stream>>>(src, dst, cnt, csr16);
    k_cvt<<<12500, 256, 0, stream>>>(x, cnt, X16, RsX);

    // fused layers, int16 gather tables + per-row scales; layer 3 pools in-kernel
    k_layer<<<3125, 256, 0, stream>>>(X16, RsX, csr16, cnt, Whi, Wlo, b0, 1,
                                      0, batch, sums, maxs, hA, RsA);
    k_layer<<<3125, 256, 0, stream>>>(hA, RsA, csr16, cnt, Whi + 16384, Wlo + 16384, b1, 1,
                                      0, batch, sums, maxs, hB, RsB);
    k_layer<<<3125, 256, 0, stream>>>(hB, RsB, csr16, cnt, Whi + 32768, Wlo + 32768, b2, 0,
                                      1, batch, sums, maxs, hA, RsA);

    k_final<<<NGRAPH, 256, 0, stream>>>(sums, maxs, counts, Wa, ba, out);
}

// Round 5
// 271.878 us; speedup vs baseline: 1.7207x; 1.0442x over previous
//
#include <hip/hip_runtime.h>
#include <stdint.h>

#define N_NODES 50000
#define N_EDGES 800000
#define HID 128
#define NCLS 10
#define NGRAPH 64
#define CAP 64   // bucket capacity; deg ~ Poisson(16), P(max>64) < 1e-20

typedef unsigned short ushort_t;
typedef __attribute__((ext_vector_type(8))) short bf16x8;
typedef __attribute__((ext_vector_type(4))) float f32x4;
typedef __attribute__((ext_vector_type(4))) _Float16 f16x4;
typedef __attribute__((ext_vector_type(8))) _Float16 f16x8;

__device__ __forceinline__ ushort_t f2bf(float f) {
    union { float f; unsigned int i; } v; v.f = f;
    unsigned int u = v.i;
    return (ushort_t)((u + 0x7FFFu + ((u >> 16) & 1u)) >> 16);
}
__device__ __forceinline__ float bf2f(ushort_t u) {
    union { unsigned int i; float f; } v; v.i = ((unsigned int)u) << 16; return v.f;
}
// UNSIGNED extraction — (p>>16) on signed int sign-extends for ids>=32768
__device__ __forceinline__ int exhi(int p) { return (p >> 16) & 0xffff; }
__device__ __forceinline__ int exlo(int p) { return p & 0xffff; }
// fp16 gather accumulate: a += (float)v[k]
__device__ __forceinline__ void add4h(float4& a, f16x4 v) {
    a.x += (float)v[0];
    a.y += (float)v[1];
    a.z += (float)v[2];
    a.w += (float)v[3];
}

// ---- fused: zero cnt/sums/maxs (blocks 0..195) + bounds (196) + wsplit (197..388)
__global__ void k_zero(int* cnt, float* sums, float* maxs,
                       const int* __restrict__ batch, int* bound, int* counts,
                       const float* __restrict__ W0, const float* __restrict__ W1,
                       const float* __restrict__ W2, ushort_t* Whi, ushort_t* Wlo) {
    int b = blockIdx.x, t = threadIdx.x;
    if (b < 196) {
        int i = b * 256 + t;
        if (i < N_NODES) cnt[i] = 0;
        if (i < NGRAPH * HID) { sums[i] = 0.f; maxs[i] = 0.f; }
    } else if (b == 196) {
        int g = t;
        if (g <= NGRAPH) {
            int lo = 0, hi = N_NODES;
            while (lo < hi) {
                int mid = (lo + hi) >> 1;
                if (batch[mid] < g) lo = mid + 1; else hi = mid;
            }
            bound[g] = lo;
        }
        __syncthreads();
        if (g < NGRAPH) counts[g] = bound[g + 1] - bound[g];
    } else {
        int gid = (b - 197) * 256 + t;          // 192*256 = 49152 items
        int l = gid / (32 * 512);
        int rem = gid - l * 32 * 512;
        int tile = rem >> 9;
        int p = rem & 511;
        int lane = p >> 3, j = p & 7;
        int kk = tile >> 3, c = tile & 7;
        int k = 32 * kk + (lane >> 4) * 8 + j;
        int n = 16 * c + (lane & 15);
        const float* W = (l == 0) ? W0 : (l == 1) ? W1 : W2;
        float x = W[k * 128 + n];
        ushort_t hi = f2bf(x);
        ushort_t lo = f2bf(x - bf2f(hi));
        Whi[l * 16384 + rem] = hi;
        Wlo[l * 16384 + rem] = lo;
    }
}

// ---- one-pass bucket-CSR fill, 8 edges/thread for atomic MLP ----
__global__ void k_fill(const int* __restrict__ src, const int* __restrict__ dst,
                       int* cnt, ushort_t* csr16) {
    int base = (blockIdx.x * 256 + threadIdx.x) * 8;
    if (base + 7 < N_EDGES) {
        int4 da = *(const int4*)(dst + base);
        int4 db = *(const int4*)(dst + base + 4);
        int4 sa = *(const int4*)(src + base);
        int4 sb = *(const int4*)(src + base + 4);
        int p0 = atomicAdd(&cnt[da.x], 1);
        int p1 = atomicAdd(&cnt[da.y], 1);
        int p2 = atomicAdd(&cnt[da.z], 1);
        int p3 = atomicAdd(&cnt[da.w], 1);
        int p4 = atomicAdd(&cnt[db.x], 1);
        int p5 = atomicAdd(&cnt[db.y], 1);
        int p6 = atomicAdd(&cnt[db.z], 1);
        int p7 = atomicAdd(&cnt[db.w], 1);
        if (p0 < CAP) csr16[da.x * CAP + p0] = (ushort_t)sa.x;
        if (p1 < CAP) csr16[da.y * CAP + p1] = (ushort_t)sa.y;
        if (p2 < CAP) csr16[da.z * CAP + p2] = (ushort_t)sa.z;
        if (p3 < CAP) csr16[da.w * CAP + p3] = (ushort_t)sa.w;
        if (p4 < CAP) csr16[db.x * CAP + p4] = (ushort_t)sb.x;
        if (p5 < CAP) csr16[db.y * CAP + p5] = (ushort_t)sb.y;
        if (p6 < CAP) csr16[db.z * CAP + p6] = (ushort_t)sb.z;
        if (p7 < CAP) csr16[db.w * CAP + p7] = (ushort_t)sb.w;
    } else {
        for (int i = base; i < N_EDGES; i++) {
            int d = dst[i];
            int slot = atomicAdd(&cnt[d], 1);
            if (slot < CAP) csr16[d * CAP + slot] = (ushort_t)src[i];
        }
    }
}

// ---- convert x -> fp16 rows, pre-scaled by 1/sqrt(deg+1) ----
__global__ void k_cvt(const float* __restrict__ x, const int* __restrict__ cnt,
                      _Float16* __restrict__ X16) {
    int gid = blockIdx.x * 256 + threadIdx.x;     // 50000*16 = 800000 exact
    int i = gid >> 4, seg = gid & 15;             // seg: 8-feature octet
    float isd = rsqrtf((float)cnt[i] + 1.0f);
    const f32x4* px = (const f32x4*)(x + (size_t)i * HID + seg * 8);
    f32x4 a = px[0], b = px[1];
    f16x8 o;
    o[0] = (_Float16)(isd * a.x); o[1] = (_Float16)(isd * a.y);
    o[2] = (_Float16)(isd * a.z); o[3] = (_Float16)(isd * a.w);
    o[4] = (_Float16)(isd * b.x); o[5] = (_Float16)(isd * b.y);
    o[6] = (_Float16)(isd * b.z); o[7] = (_Float16)(isd * b.w);
    *(f16x8*)(X16 + (size_t)i * HID + seg * 8) = o;
}

// ---------------- fused layer: round-0-verified gather control flow ---------------
// Table = fp16 of isd_j * h_j. Wave wv: nodes blk*16+wv*4+r.
// Lane split (round 0): hl = lane&31 -> 4-feature group (8B); q = lane>>5 -> edge parity.
__global__ void k_layer(const _Float16* __restrict__ In,
                        const ushort_t* __restrict__ csr16, const int* __restrict__ cnt,
                        const ushort_t* __restrict__ Whi, const ushort_t* __restrict__ Wlo,
                        const float* __restrict__ bias, int scale_out,
                        int pool, const int* __restrict__ batch,
                        float* sums, float* maxs, _Float16* __restrict__ Out) {
    __shared__ float T[16][132];
    __shared__ int sg[16];
    int t = threadIdx.x, wv = t >> 6, lane = t & 63;
    int hl = lane & 31, q = lane >> 5;   // half-lane, half-index (round-0 layout)
    if (pool && t < 16) sg[t] = batch[blockIdx.x * 16 + t];

    // ---- gather phase: wave wv aggregates nodes (block*16 + wv*4 + r)
    for (int r = 0; r < 4; r++) {
        int i = blockIdx.x * 16 + wv * 4 + r;      // 3125*16 = 50000 exact
        int ci = cnt[i];
        int m = min(ci, CAP);
        float isdi = rsqrtf((float)ci + 1.0f);
        // preload full index row: int k holds edges 2k (lo16), 2k+1 (hi16)
        int packed = ((const int*)(csr16 + (size_t)i * CAP))[hl];
        float4 a0 = make_float4(0.f, 0.f, 0.f, 0.f);
        float4 a1 = a0, a2 = a0, a3 = a0;
        if (q == 0) {
            f16x4 sv = *(const f16x4*)(In + (size_t)i * HID + hl * 4);
            add4h(a0, sv);                         // self term (pre-scaled table)
        }
        int e = 0;
        for (; e + 7 < m; e += 8) {
            int k0 = e >> 1;
            int p0 = __shfl(packed, k0);
            int p1 = __shfl(packed, k0 + 1);
            int p2 = __shfl(packed, k0 + 2);
            int p3 = __shfl(packed, k0 + 3);
            int s0 = q ? exhi(p0) : exlo(p0);
            int s1 = q ? exhi(p1) : exlo(p1);
            int s2 = q ? exhi(p2) : exlo(p2);
            int s3 = q ? exhi(p3) : exlo(p3);
            f16x4 v0 = *(const f16x4*)(In + (size_t)s0 * HID + hl * 4);
            f16x4 v1 = *(const f16x4*)(In + (size_t)s1 * HID + hl * 4);
            f16x4 v2 = *(const f16x4*)(In + (size_t)s2 * HID + hl * 4);
            f16x4 v3 = *(const f16x4*)(In + (size_t)s3 * HID + hl * 4);
            add4h(a0, v0); add4h(a1, v1); add4h(a2, v2); add4h(a3, v3);
        }
        for (; e + 1 < m; e += 2) {
            int p = __shfl(packed, e >> 1);
            int s0 = q ? exhi(p) : exlo(p);
            f16x4 v0 = *(const f16x4*)(In + (size_t)s0 * HID + hl * 4);
            add4h(a0, v0);
        }
        if (e < m && q == 0) {
            int p = __shfl(packed, e >> 1);
            int s0 = exlo(p);
            f16x4 v0 = *(const f16x4*)(In + (size_t)s0 * HID + hl * 4);
            add4h(a0, v0);
        }
        float4 s4;
        s4.x = (a0.x + a1.x) + (a2.x + a3.x);
        s4.y = (a0.y + a1.y) + (a2.y + a3.y);
        s4.z = (a0.z + a1.z) + (a2.z + a3.z);
        s4.w = (a0.w + a1.w) + (a2.w + a3.w);
        // combine the two halves (lane ^ 32 partner holds the other parity's sum)
        s4.x += __shfl_xor(s4.x, 32);
        s4.y += __shfl_xor(s4.y, 32);
        s4.z += __shfl_xor(s4.z, 32);
        s4.w += __shfl_xor(s4.w, 32);
        if (q == 0) {
            float4 o;
            o.x = isdi * s4.x; o.y = isdi * s4.y;
            o.z = isdi * s4.z; o.w = isdi * s4.w;
            *(float4*)&T[wv * 4 + r][hl * 4] = o;
        }
    }
    __syncthreads();

    // ---- MFMA phase: wave wv -> cols [wv*32, wv*32+32)
    int mrow = lane & 15, qq = lane >> 4;
    f32x4 acc[2];
    acc[0] = (f32x4){0.f, 0.f, 0.f, 0.f};
    acc[1] = (f32x4){0.f, 0.f, 0.f, 0.f};
#pragma unroll
    for (int kk = 0; kk < 4; kk++) {
        const float* tp = &T[mrow][kk * 32 + qq * 8];
        float4 p0 = *(const float4*)tp;
        float4 p1 = *(const float4*)(tp + 4);
        float av[8] = {p0.x, p0.y, p0.z, p0.w, p1.x, p1.y, p1.z, p1.w};
        bf16x8 ahi, alo;
#pragma unroll
        for (int j = 0; j < 8; j++) {
            ushort_t hbits = f2bf(av[j]);
            ahi[j] = (short)hbits;
            alo[j] = (short)f2bf(av[j] - bf2f(hbits));
        }
#pragma unroll
        for (int cl = 0; cl < 2; cl++) {
            int c = wv * 2 + cl;
            const bf16x8 bhi = *(const bf16x8*)(Whi + (((kk * 8 + c) * 64 + lane) << 3));
            const bf16x8 blo = *(const bf16x8*)(Wlo + (((kk * 8 + c) * 64 + lane) << 3));
            acc[cl] = __builtin_amdgcn_mfma_f32_16x16x32_bf16(ahi, bhi, acc[cl], 0, 0, 0);
            acc[cl] = __builtin_amdgcn_mfma_f32_16x16x32_bf16(alo, bhi, acc[cl], 0, 0, 0);
            acc[cl] = __builtin_amdgcn_mfma_f32_16x16x32_bf16(ahi, blo, acc[cl], 0, 0, 0);
        }
    }
    // epilogue: C/D col = mrow, row = qq*4+rr
    int rb = blockIdx.x * 16 + qq * 4;
    if (!pool) {
        float osc[4];
#pragma unroll
        for (int rr = 0; rr < 4; rr++)
            osc[rr] = scale_out ? rsqrtf((float)cnt[rb + rr] + 1.0f) : 1.0f;
#pragma unroll
        for (int cl = 0; cl < 2; cl++) {
            int col = (wv * 2 + cl) * 16 + mrow;
            float bcol = bias[col];
#pragma unroll
            for (int rr = 0; rr < 4; rr++) {
                float val = fmaxf(acc[cl][rr] + bcol, 0.f);
                Out[(size_t)(rb + rr) * HID + col] = (_Float16)(val * osc[rr]);
            }
        }
    } else {
        // write relu'd values back into T (rows x feats), then block pool-reduce
        __syncthreads();   // all waves done reading T
#pragma unroll
        for (int cl = 0; cl < 2; cl++) {
            int col = (wv * 2 + cl) * 16 + mrow;
            float bcol = bias[col];
#pragma unroll
            for (int rr = 0; rr < 4; rr++)
                T[qq * 4 + rr][col] = fmaxf(acc[cl][rr] + bcol, 0.f);
        }
        __syncthreads();
        int f = t & 127, half = t >> 7;   // half 0: sums, half 1: maxs
        int cur = sg[0];
        float s = 0.f, mx = 0.f;
        for (int r = 0; r < 16; r++) {
            int g = sg[r];
            if (g != cur) {
                if (half == 0) atomicAdd(&sums[cur * HID + f], s);
                else atomicMax((int*)&maxs[cur * HID + f], __float_as_int(mx));
                s = 0.f; mx = 0.f; cur = g;
            }
            float v = T[r][f];
            s += v;
            mx = fmaxf(mx, v);
        }
        if (half == 0) atomicAdd(&sums[cur * HID + f], s);
        else atomicMax((int*)&maxs[cur * HID + f], __float_as_int(mx));
    }
}

// ---------------- head ----------------
__global__ void k_final(const float* __restrict__ sums, const float* __restrict__ maxs,
                        const int* __restrict__ counts, const float* __restrict__ Wa,
                        const float* __restrict__ ba, float* __restrict__ out) {
    __shared__ float a[256];
    __shared__ float red[4];
    int g = blockIdx.x, t = threadIdx.x;
    float denom = fmaxf((float)counts[g], 1.f);
    float val = (t < 128) ? (sums[g * HID + t] / denom) : maxs[g * HID + (t - 128)];
    a[t] = val;
    out[NGRAPH * NCLS + g * 256 + t] = val;
    __syncthreads();
    for (int c = 0; c < NCLS; c++) {
        float p = a[t] * Wa[t * NCLS + c];
        for (int o = 32; o > 0; o >>= 1) p += __shfl_down(p, o);
        if ((t & 63) == 0) red[t >> 6] = p;
        __syncthreads();
        if (t == 0) {
            out[g * NCLS + c] = red[0] + red[1] + red[2] + red[3] + ba[c];
        }
        __syncthreads();
    }
}

extern "C" void kernel_launch(void* const* d_in, const int* in_sizes, int n_in,
                              void* d_out, int out_size, void* d_ws, size_t ws_size,
                              hipStream_t stream) {
    const float* x = (const float*)d_in[0];
    const int* ei = (const int*)d_in[1];
    const int* src = ei;
    const int* dst = ei + N_EDGES;
    const int* batch = (const int*)d_in[2];
    const float* W0 = (const float*)d_in[3];
    const float* b0 = (const float*)d_in[4];
    const float* W1 = (const float*)d_in[5];
    const float* b1 = (const float*)d_in[6];
    const float* W2 = (const float*)d_in[7];
    const float* b2 = (const float*)d_in[8];
    const float* Wa = (const float*)d_in[9];
    const float* ba = (const float*)d_in[10];
    float* out = (float*)d_out;

    char* ws = (char*)d_ws;
    int*       cnt    = (int*)(ws + 0);             // 50000 i32
    int*       bound  = (int*)(ws + 200192);        // 65 i32
    int*       counts = (int*)(ws + 200576);        // 64 i32
    float*     sums   = (float*)(ws + 200832);      // 8192 f32
    float*     maxs   = (float*)(ws + 233600);      // 8192 f32
    ushort_t*  Whi    = (ushort_t*)(ws + 266368);   // 3*16384 bf16
    ushort_t*  Wlo    = (ushort_t*)(ws + 364672);   // 3*16384 bf16
    ushort_t*  csr16  = (ushort_t*)(ws + 462976);   // 50000*64 u16 (6.4 MB)
    _Float16*  X16    = (_Float16*)(ws + 7462976);  // 50000x128 f16 (12.8 MB)
    _Float16*  hA     = (_Float16*)(ws + 20262976); // 50000x128 f16
    _Float16*  hB     = (_Float16*)(ws + 33062976); // 50000x128 f16
    // total 45,862,976 B

    k_zero<<<389, 256, 0, stream>>>(cnt, sums, maxs, batch, bound, counts,
                                    W0, W1, W2, Whi, Wlo);
    k_fill<<<391, 256, 0, stream>>>(src, dst, cnt, csr16);
    k_cvt<<<3125, 256, 0, stream>>>(x, cnt, X16);

    // fused layers, fp16 gather tables (pre-scaled); layer 3 pools in-kernel
    k_layer<<<3125, 256, 0, stream>>>(X16, csr16, cnt, Whi, Wlo, b0, 1,
                                      0, batch, sums, maxs, hA);
    k_layer<<<3125, 256, 0, stream>>>(hA, csr16, cnt, Whi + 16384, Wlo + 16384, b1, 1,
                                      0, batch, sums, maxs, hB);
    k_layer<<<3125, 256, 0, stream>>>(hB, csr16, cnt, Whi + 32768, Wlo + 32768, b2, 0,
                                      1, batch, sums, maxs, hA);

    k_final<<<NGRAPH, 256, 0, stream>>>(sums, maxs, counts, Wa, ba, out);
}